// Round 1
// baseline (414.716 us; speedup 1.0000x reference)
//
#include <hip/hip_runtime.h>

#define TPB 256

// DepthConv: B=2, C_in=C_out=32, H=W=512, 3x3, pad=1, stride=1, dil=1.
// out[b,o,h,w] = bias[o] + sum_{tap,c} W[o,c,tap] * x[b,c,nbr] * exp(-8.3*|dc-dn|)
// Zero-padded x => out-of-bounds taps contribute 0 exactly -> skip them.
__global__ __launch_bounds__(TPB) void depthconv_fp32_kernel(
    const float* __restrict__ x,
    const float* __restrict__ depth,
    const float* __restrict__ weight,
    const float* __restrict__ bias,
    float* __restrict__ out)
{
    constexpr int C = 32, H = 512, W = 512, HW = H * W;

    // Weight staged in LDS transposed to [tap][c][o] so the inner o-loop is
    // contiguous float4 reads, same address across the wave (broadcast).
    __shared__ float wlds[9][32][32];
    __shared__ float blds[32];

    for (int i = threadIdx.x; i < 9 * 32 * 32; i += TPB) {
        // weight natural layout: idx = ((o*32 + c)*3 + ki)*3 + kj
        int tap = i % 9;
        int oc  = i / 9;
        int c   = oc & 31;
        int o   = oc >> 5;
        wlds[tap][c][o] = weight[i];
    }
    if (threadIdx.x < 32) blds[threadIdx.x] = bias[threadIdx.x];
    __syncthreads();

    // One thread per output pixel; consecutive threads -> consecutive w
    // (coalesced on x, depth, out).
    int gid = blockIdx.x * TPB + threadIdx.x;   // 0 .. B*H*W-1
    int b   = gid >> 18;                        // HW = 2^18
    int hw  = gid & (HW - 1);
    int h   = hw >> 9;
    int w   = hw & (W - 1);

    const float dc = depth[b * HW + hw];

    float acc[32];
    #pragma unroll
    for (int o = 0; o < 32; ++o) acc[o] = blds[o];

    const float* xb = x + b * (C * HW);
    const float* db = depth + b * HW;

    for (int ki = 0; ki < 3; ++ki) {
        int hi = h + ki - 1;
        if (hi < 0 || hi >= H) continue;
        for (int kj = 0; kj < 3; ++kj) {
            int wj = w + kj - 1;
            if (wj < 0 || wj >= W) continue;
            int tap = ki * 3 + kj;

            float ds = db[hi * W + wj];
            float s  = __expf(-8.3f * fabsf(dc - ds));

            const float* xp = xb + hi * W + wj;   // + c*HW per channel
            #pragma unroll 4
            for (int c = 0; c < 32; ++c) {
                float xv = xp[c * HW] * s;
                const float4* wq = (const float4*)wlds[tap][c];
                #pragma unroll
                for (int o4 = 0; o4 < 8; ++o4) {
                    float4 wv = wq[o4];
                    acc[o4 * 4 + 0] = fmaf(wv.x, xv, acc[o4 * 4 + 0]);
                    acc[o4 * 4 + 1] = fmaf(wv.y, xv, acc[o4 * 4 + 1]);
                    acc[o4 * 4 + 2] = fmaf(wv.z, xv, acc[o4 * 4 + 2]);
                    acc[o4 * 4 + 3] = fmaf(wv.w, xv, acc[o4 * 4 + 3]);
                }
            }
        }
    }

    float* op = out + b * (C * HW) + hw;
    #pragma unroll
    for (int o = 0; o < 32; ++o) op[o * HW] = acc[o];
}

extern "C" void kernel_launch(void* const* d_in, const int* in_sizes, int n_in,
                              void* d_out, int out_size, void* d_ws, size_t ws_size,
                              hipStream_t stream) {
    const float* x      = (const float*)d_in[0];
    const float* depth  = (const float*)d_in[1];
    const float* weight = (const float*)d_in[2];
    const float* bias   = (const float*)d_in[3];
    float* out          = (float*)d_out;

    constexpr int total = 2 * 512 * 512;        // B*H*W pixels
    dim3 grid(total / TPB), block(TPB);
    hipLaunchKernelGGL(depthconv_fp32_kernel, grid, block, 0, stream,
                       x, depth, weight, bias, out);
}

// Round 2
// 237.559 us; speedup vs baseline: 1.7457x; 1.7457x over previous
//
#include <hip/hip_runtime.h>
#include <hip/hip_bf16.h>

typedef short short8 __attribute__((ext_vector_type(8)));
typedef float floatx4 __attribute__((ext_vector_type(4)));

#define TPB 256
#define TH 4            // output rows per block (one per wave)
#define TW 64           // output pixels (w) per block
#define XP 66           // LDS pixel pitch (TW + 2 halo); stride 66 -> 2-way bank alias (free)

__device__ __forceinline__ short bf16b(float f) {
    __hip_bfloat16 h = __float2bfloat16(f);
    return __builtin_bit_cast(short, h);
}

// out[b,o,h,w] = bias[o] + sum_{tap,c} W[o,c,tap] * x[b,c,nbr] * exp(-8.3*|dc-dn|)
// As 9 GEMMs: per tap, M=C_out=32 (2 MFMA halves), K=C_in=32, N=pixels.
// sim is per-(pixel,tap) -> folds into the B operand only.
__global__ __launch_bounds__(TPB) void depthconv_mfma(
    const float* __restrict__ x,
    const float* __restrict__ depth,
    const float* __restrict__ weight,
    const float* __restrict__ bias,
    float* __restrict__ out)
{
    constexpr int C = 32, H = 512, W = 512, HW = H * W;

    __shared__ float xt[TH + 2][C][XP];   // fp32 x tile incl. 1-px halo
    __shared__ float dt[TH + 2][XP];      // depth tile incl. halo

    const int bid  = blockIdx.x;
    const int wseg = bid & 7;             // 512/64 = 8
    const int hseg = (bid >> 3) & 127;    // 512/4 = 128
    const int b    = bid >> 10;
    const int h0 = hseg * TH, w0 = wseg * TW;

    // ---- stage x tile (zero outside image => border taps contribute 0 exactly)
    const float* xb = x + b * (C * HW);
    for (int i = threadIdx.x; i < (TH + 2) * C * XP; i += TPB) {
        int px = i % XP;
        int rc = i / XP;
        int c  = rc % C;
        int r  = rc / C;
        int hh = h0 - 1 + r;
        int ww = w0 - 1 + px;
        float v = 0.f;
        if ((unsigned)hh < (unsigned)H && (unsigned)ww < (unsigned)W)
            v = xb[c * HW + hh * W + ww];
        xt[r][c][px] = v;
    }
    const float* db = depth + b * HW;
    for (int i = threadIdx.x; i < (TH + 2) * XP; i += TPB) {
        int px = i % XP, r = i / XP;
        int hh = h0 - 1 + r, ww = w0 - 1 + px;
        float v = 0.f;
        if ((unsigned)hh < (unsigned)H && (unsigned)ww < (unsigned)W)
            v = db[hh * W + ww];
        dt[r][px] = v;
    }

    const int lane = threadIdx.x & 63;
    const int wid  = threadIdx.x >> 6;    // wave id = output row within tile
    const int nn   = lane & 15;           // n (pixel) for B; m (o) for A; col for C/D
    const int q    = lane >> 4;           // k-group: k = 8q + j

    // ---- A fragments: weights as bf16, layout A[m=lane&15][k=8*(lane>>4)+j]
    // natural weight layout: ((o*32 + c)*3 + ki)*3 + kj = (o*32+c)*9 + tap
    short8 afrag[2][9];
    #pragma unroll
    for (int half = 0; half < 2; ++half) {
        int o = half * 16 + nn;
        #pragma unroll
        for (int tap = 0; tap < 9; ++tap) {
            short8 f;
            #pragma unroll
            for (int j = 0; j < 8; ++j)
                f[j] = bf16b(weight[(o * 32 + q * 8 + j) * 9 + tap]);
            afrag[half][tap] = f;
        }
    }
    // bias in C/D layout: row(o) = 4*q + reg
    float b0[4], b1[4];
    #pragma unroll
    for (int r = 0; r < 4; ++r) { b0[r] = bias[q * 4 + r]; b1[r] = bias[16 + q * 4 + r]; }

    __syncthreads();

    const int h = h0 + wid;
    #pragma unroll
    for (int t = 0; t < TW / 16; ++t) {
        floatx4 acc0, acc1;
        #pragma unroll
        for (int r = 0; r < 4; ++r) { acc0[r] = b0[r]; acc1[r] = b1[r]; }

        const float dc = dt[wid + 1][t * 16 + nn + 1];

        #pragma unroll
        for (int ki = 0; ki < 3; ++ki) {
            #pragma unroll
            for (int kj = 0; kj < 3; ++kj) {
                const int tap = ki * 3 + kj;
                float dn = dt[wid + ki][t * 16 + nn + kj];
                float s  = __expf(-8.3f * fabsf(dc - dn));
                // B[k=8q+j][n=nn]: 8 channel values of one shifted pixel, scaled by sim
                const float* xp = &xt[wid + ki][q * 8][t * 16 + nn + kj];
                short8 bf;
                #pragma unroll
                for (int j = 0; j < 8; ++j)
                    bf[j] = bf16b(xp[j * XP] * s);
                acc0 = __builtin_amdgcn_mfma_f32_16x16x32_bf16(afrag[0][tap], bf, acc0, 0, 0, 0);
                acc1 = __builtin_amdgcn_mfma_f32_16x16x32_bf16(afrag[1][tap], bf, acc1, 0, 0, 0);
            }
        }

        // C/D: col = nn (pixel), row(o) = 4q + reg
        float* op = out + b * (C * HW) + h * W + w0 + t * 16 + nn;
        #pragma unroll
        for (int r = 0; r < 4; ++r) {
            op[(q * 4 + r) * HW]      = acc0[r];
            op[(16 + q * 4 + r) * HW] = acc1[r];
        }
    }
}

extern "C" void kernel_launch(void* const* d_in, const int* in_sizes, int n_in,
                              void* d_out, int out_size, void* d_ws, size_t ws_size,
                              hipStream_t stream) {
    const float* x      = (const float*)d_in[0];
    const float* depth  = (const float*)d_in[1];
    const float* weight = (const float*)d_in[2];
    const float* bias   = (const float*)d_in[3];
    float* out          = (float*)d_out;

    // 2 batches * 128 h-segments * 8 w-segments
    dim3 grid(2 * 128 * 8), block(TPB);
    hipLaunchKernelGGL(depthconv_mfma, grid, block, 0, stream,
                       x, depth, weight, bias, out);
}

// Round 4
// 202.718 us; speedup vs baseline: 2.0458x; 1.1719x over previous
//
#include <hip/hip_runtime.h>
#include <hip/hip_bf16.h>

typedef short short8 __attribute__((ext_vector_type(8)));
typedef float floatx4 __attribute__((ext_vector_type(4)));

#define TPB 256
#define TH 4            // output rows per block (one per wave)
#define TW 64           // output pixels (w) per block
#define R6 (TH + 2)     // staged rows incl. halo
#define PXT (TW + 2)    // staged pixels per row incl. halo (66)
#define PITCH 20        // u32 (bf16-pair) pitch per pixel: 16 pairs + pad->20 (16B-aligned, bank-uniform)

__device__ __forceinline__ unsigned short bf16u(float f) {
    return __builtin_bit_cast(unsigned short, __float2bfloat16(f));
}

// out[b,o,h,w] = bias[o] + sum_{tap,c} W[o,c,tap] * x[b,c,nbr] * exp(-8.3*|dc-dn|)
// 9 tiny GEMMs on MFMA; sim folded into B. x staged in LDS as bf16 pairs,
// layout [row][px][c] so a lane's 8-channel B-slice is ONE ds_read_b128.
// exp factored: sim = min(ep_n*em_c, em_n*ep_c), exp only at staging.
__global__ __launch_bounds__(TPB) void depthconv_mfma2(
    const float* __restrict__ x,
    const float* __restrict__ depth,
    const float* __restrict__ weight,
    const float* __restrict__ bias,
    float* __restrict__ out)
{
    constexpr int C = 32, H = 512, W = 512, HW = H * W;

    __shared__ unsigned xt[R6 * PXT * PITCH];   // packed bf16 pairs, [r][px][cp]
    __shared__ float    dt[R6 * PXT * 2];       // (em, ep) per pixel

    const int bid  = blockIdx.x;
    const int wseg = bid & 7;             // 512/64 = 8
    const int hseg = (bid >> 3) & 127;    // 512/4 = 128
    const int b    = bid >> 10;
    const int h0 = hseg * TH, w0 = wseg * TW;

    // ---- stage x tile: fp32 global [c][h][w] -> bf16-pair LDS [r][px][cp]
    const float* xb = x + b * (C * HW);
    for (int i = threadIdx.x; i < R6 * PXT * (C / 2); i += TPB) {
        int px = i % PXT;
        int t  = i / PXT;
        int cp = t % (C / 2);
        int r  = t / (C / 2);
        int hh = h0 - 1 + r;
        int ww = w0 - 1 + px;
        unsigned v = 0;
        if ((unsigned)hh < (unsigned)H && (unsigned)ww < (unsigned)W) {
            const float* p = xb + (2 * cp) * HW + hh * W + ww;
            v = (unsigned)bf16u(p[0]) | ((unsigned)bf16u(p[HW]) << 16);
        }
        xt[(r * PXT + px) * PITCH + cp] = v;
    }
    // ---- stage depth as (em, ep) = exp(-8.3 d), exp(+8.3 d)
    const float* db = depth + b * HW;
    for (int i = threadIdx.x; i < R6 * PXT; i += TPB) {
        int px = i % PXT, r = i / PXT;
        int hh = h0 - 1 + r, ww = w0 - 1 + px;
        float d = 0.f;
        if ((unsigned)hh < (unsigned)H && (unsigned)ww < (unsigned)W)
            d = db[hh * W + ww];
        dt[i * 2 + 0] = __expf(-8.3f * d);
        dt[i * 2 + 1] = __expf(8.3f * d);
    }

    const int lane = threadIdx.x & 63;
    const int wid  = threadIdx.x >> 6;    // wave id = output row within tile
    const int nn   = lane & 15;           // n (pixel) for B; m (o) for A; col for C/D
    const int q    = lane >> 4;           // k-group: k = 8q + j

    // ---- A fragments: weights as bf16, layout A[m=lane&15][k=8q+j]
    // natural weight layout: (o*32 + c)*9 + tap
    short8 afrag[2][9];
    #pragma unroll
    for (int half = 0; half < 2; ++half) {
        int o = half * 16 + nn;
        #pragma unroll
        for (int tap = 0; tap < 9; ++tap) {
            short8 f;
            #pragma unroll
            for (int j = 0; j < 8; ++j)
                f[j] = (short)bf16u(weight[(o * 32 + q * 8 + j) * 9 + tap]);
            afrag[half][tap] = f;
        }
    }
    // bias in C/D layout: row(o) = 4q + reg
    float b0[4], b1[4];
    #pragma unroll
    for (int r = 0; r < 4; ++r) { b0[r] = bias[q * 4 + r]; b1[r] = bias[16 + q * 4 + r]; }

    __syncthreads();

    const int h = h0 + wid;
    #pragma unroll
    for (int t = 0; t < TW / 16; ++t) {
        floatx4 acc0, acc1;
        #pragma unroll
        for (int r = 0; r < 4; ++r) { acc0[r] = b0[r]; acc1[r] = b1[r]; }

        const int cpx = (wid + 1) * PXT + t * 16 + nn + 1;
        const float em_c = dt[cpx * 2 + 0];
        const float ep_c = dt[cpx * 2 + 1];

        #pragma unroll
        for (int ki = 0; ki < 3; ++ki) {
            #pragma unroll
            for (int kj = 0; kj < 3; ++kj) {
                const int tap = ki * 3 + kj;
                const int npx = (wid + ki) * PXT + t * 16 + nn + kj;
                float em_n = dt[npx * 2 + 0];
                float ep_n = dt[npx * 2 + 1];
                float s = fminf(ep_n * em_c, em_n * ep_c);   // exp(-8.3|dc-dn|)

                // one b128: 8 channels (bf16 pairs) of this lane's pixel
                const uint4 xv = *(const uint4*)&xt[npx * PITCH + q * 4];
                unsigned pk[4];
                const unsigned uu[4] = { xv.x, xv.y, xv.z, xv.w };
                #pragma unroll
                for (int p = 0; p < 4; ++p) {
                    unsigned u = uu[p];
                    float lo = __builtin_bit_cast(float, u << 16) * s;
                    float hi = __builtin_bit_cast(float, u & 0xffff0000u) * s;
                    pk[p] = (unsigned)bf16u(lo) | ((unsigned)bf16u(hi) << 16);
                }
                short8 bfrag = __builtin_bit_cast(short8, *(const uint4*)pk);

                acc0 = __builtin_amdgcn_mfma_f32_16x16x32_bf16(afrag[0][tap], bfrag, acc0, 0, 0, 0);
                acc1 = __builtin_amdgcn_mfma_f32_16x16x32_bf16(afrag[1][tap], bfrag, acc1, 0, 0, 0);
            }
        }

        // C/D: col = nn (pixel), row(o) = 4q + reg
        float* op = out + b * (C * HW) + h * W + w0 + t * 16 + nn;
        #pragma unroll
        for (int r = 0; r < 4; ++r) {
            op[(q * 4 + r) * HW]      = acc0[r];
            op[(16 + q * 4 + r) * HW] = acc1[r];
        }
    }
}

extern "C" void kernel_launch(void* const* d_in, const int* in_sizes, int n_in,
                              void* d_out, int out_size, void* d_ws, size_t ws_size,
                              hipStream_t stream) {
    const float* x      = (const float*)d_in[0];
    const float* depth  = (const float*)d_in[1];
    const float* weight = (const float*)d_in[2];
    const float* bias   = (const float*)d_in[3];
    float* out          = (float*)d_out;

    // 2 batches * 128 h-segments * 8 w-segments
    dim3 grid(2 * 128 * 8), block(TPB);
    hipLaunchKernelGGL(depthconv_mfma2, grid, block, 0, stream,
                       x, depth, weight, bias, out);
}

// Round 5
// 166.736 us; speedup vs baseline: 2.4873x; 1.2158x over previous
//
#include <hip/hip_runtime.h>
#include <hip/hip_bf16.h>

typedef short short8 __attribute__((ext_vector_type(8)));
typedef float floatx4 __attribute__((ext_vector_type(4)));

constexpr int C  = 32, H = 512, W = 512, HW = H * W;
constexpr int Hp = 514, Wp = 514;               // padded (1-px halo)
constexpr int NPX = 2 * Hp * Wp;                // padded pixels, both batches

// ws layout (bytes): x_pack (padded NHWC bf16) | d_pack (float2 em,ep) | w_pack
constexpr size_t XOFF = 0;
constexpr size_t XSZ  = (size_t)NPX * 64;        // 32 ch * 2 B
constexpr size_t DOFF = XOFF + XSZ;              // 33,817,088 (16B aligned)
constexpr size_t DSZ  = (size_t)NPX * 8;
constexpr size_t WOFF = DOFF + DSZ;              // 38,044,224 (16B aligned)
// total required: 38,062,656 B (~36.3 MB) <= ws_size

__device__ __forceinline__ unsigned short bf16u(float f) {
    return __builtin_bit_cast(unsigned short, __float2bfloat16(f));
}
__device__ __forceinline__ unsigned pack2(float lo, float hi) {
    return (unsigned)bf16u(lo) | ((unsigned)bf16u(hi) << 16);
}

// ---- x: NCHW fp32 -> padded NHWC bf16 (64 B per pixel). LDS transpose.
__global__ __launch_bounds__(256) void pack_x(const float* __restrict__ x,
                                              unsigned* __restrict__ xp) {
    __shared__ float t[C][65];                   // pitch 65 -> 2-way bank alias (free)
    const int bid = blockIdx.x;                  // b(2) x h(512) x wseg(8)
    const int wseg = bid & 7, h = (bid >> 3) & 511, b = bid >> 12;
    const int w0 = wseg * 64;
    const int tid = threadIdx.x;

    const float* xb = x + (size_t)b * C * HW + h * W + w0;
    #pragma unroll
    for (int p = 0; p < 2; ++p) {
        int c = p * 16 + (tid >> 4), f4 = tid & 15;
        float4 v = *(const float4*)(xb + (size_t)c * HW + f4 * 4);
        t[c][f4 * 4 + 0] = v.x; t[c][f4 * 4 + 1] = v.y;
        t[c][f4 * 4 + 2] = v.z; t[c][f4 * 4 + 3] = v.w;
    }
    __syncthreads();

    const int px = tid >> 2, q = tid & 3;
    uint4 o;
    o.x = pack2(t[q * 8 + 0][px], t[q * 8 + 1][px]);
    o.y = pack2(t[q * 8 + 2][px], t[q * 8 + 3][px]);
    o.z = pack2(t[q * 8 + 4][px], t[q * 8 + 5][px]);
    o.w = pack2(t[q * 8 + 6][px], t[q * 8 + 7][px]);
    size_t ppx = ((size_t)(b * Hp + h + 1)) * Wp + (w0 + 1 + px);
    *(uint4*)(xp + ppx * 16 + q * 4) = o;
}

// ---- depth -> padded (exp(-8.3 d), exp(+8.3 d))
__global__ __launch_bounds__(256) void pack_d(const float* __restrict__ depth,
                                              float2* __restrict__ dpk) {
    int gid = blockIdx.x * 256 + threadIdx.x;    // 2*HW threads
    int b = gid >> 18, hw = gid & (HW - 1), h = hw >> 9, w = hw & 511;
    float d = depth[gid];
    size_t ppx = ((size_t)(b * Hp + h + 1)) * Wp + (w + 1);
    dpk[ppx] = make_float2(__expf(-8.3f * d), __expf(8.3f * d));
}

// ---- zero the halo border of x_pack / d_pack (=> border taps contribute 0 exactly)
__global__ __launch_bounds__(256) void pack_border(unsigned* __restrict__ xp,
                                                   float2* __restrict__ dpk) {
    int i = blockIdx.x * 256 + threadIdx.x;
    if (i >= 4104) return;                       // 2 * (2*514 + 2*512)
    int b = i / 2052, r = i % 2052;
    int hh, ww;
    if (r < 514)       { hh = 0;   ww = r; }
    else if (r < 1028) { hh = 513; ww = r - 514; }
    else { int j = r - 1028; hh = 1 + (j >> 1); ww = (j & 1) ? 513 : 0; }
    size_t ppx = ((size_t)(b * Hp + hh)) * Wp + ww;
    uint4 z = {0u, 0u, 0u, 0u};
    uint4* p = (uint4*)(xp + ppx * 16);
    p[0] = z; p[1] = z; p[2] = z; p[3] = z;
    dpk[ppx] = make_float2(0.f, 0.f);
}

// ---- weights -> per-lane A-fragment uint4s: wp[(tap*2+half)*64 + lane]
// A layout for mfma_f32_16x16x32_bf16: A[m=lane&15][k=8*(lane>>4)+j]
__global__ __launch_bounds__(256) void pack_w(const float* __restrict__ weight,
                                              uint4* __restrict__ wp) {
    int i = blockIdx.x * 256 + threadIdx.x;
    if (i >= 1152) return;                       // 9 taps * 2 halves * 64 lanes
    int lane = i & 63, half = (i >> 6) & 1, tap = i >> 7;
    int o = half * 16 + (lane & 15), q = lane >> 4;
    uint4 v;
    unsigned pk[4];
    #pragma unroll
    for (int p = 0; p < 4; ++p) {
        float lo = weight[(o * 32 + q * 8 + 2 * p) * 9 + tap];
        float hi = weight[(o * 32 + q * 8 + 2 * p + 1) * 9 + tap];
        pk[p] = pack2(lo, hi);
    }
    v.x = pk[0]; v.y = pk[1]; v.z = pk[2]; v.w = pk[3];
    wp[i] = v;
}

// ---- main conv: no LDS, no syncthreads. B-frag = one coalesced dwordx4 per lane.
__global__ __launch_bounds__(256) void depthconv_main(
    const unsigned* __restrict__ xp,
    const float2*   __restrict__ dpk,
    const uint4*    __restrict__ wp,
    const float*    __restrict__ bias,
    float*          __restrict__ out)
{
    const int bid  = blockIdx.x;                 // b(2) x h(512) x wseg(8)
    const int wseg = bid & 7, h = (bid >> 3) & 511, b = bid >> 12;
    const int lane = threadIdx.x & 63, wid = threadIdx.x >> 6;
    const int nn   = lane & 15, q = lane >> 4;
    const int pw   = wseg * 64 + wid * 16 + nn;  // output column 0..511

    // A fragments (18 x 16 B, L1-hot)
    short8 af[2][9];
    #pragma unroll
    for (int tap = 0; tap < 9; ++tap) {
        af[0][tap] = __builtin_bit_cast(short8, wp[(tap * 2 + 0) * 64 + lane]);
        af[1][tap] = __builtin_bit_cast(short8, wp[(tap * 2 + 1) * 64 + lane]);
    }

    floatx4 acc0, acc1;                          // C/D: col=nn, row(o)=4q+reg
    #pragma unroll
    for (int r = 0; r < 4; ++r) {
        acc0[r] = bias[q * 4 + r];
        acc1[r] = bias[16 + q * 4 + r];
    }

    const size_t rowbase = ((size_t)(b * Hp + h)) * Wp + pw;  // padded (h+ki, pw+kj)
    const float2 dc = dpk[rowbase + Wp + 1];     // center (em_c, ep_c)

    #pragma unroll
    for (int ki = 0; ki < 3; ++ki) {
        #pragma unroll
        for (int kj = 0; kj < 3; ++kj) {
            const int tap = ki * 3 + kj;
            const size_t np = rowbase + (size_t)ki * Wp + kj;
            float2 dn = dpk[np];
            float s = fminf(dn.y * dc.x, dn.x * dc.y);     // exp(-8.3|dc-dn|)

            const uint4 xv = *(const uint4*)(xp + np * 16 + q * 4);
            const unsigned uu[4] = { xv.x, xv.y, xv.z, xv.w };
            unsigned pk[4];
            #pragma unroll
            for (int p = 0; p < 4; ++p) {
                unsigned u = uu[p];
                float lo = __builtin_bit_cast(float, u << 16) * s;
                float hi = __builtin_bit_cast(float, u & 0xffff0000u) * s;
                pk[p] = pack2(lo, hi);
            }
            short8 bfrag = __builtin_bit_cast(short8, *(const uint4*)pk);

            acc0 = __builtin_amdgcn_mfma_f32_16x16x32_bf16(af[0][tap], bfrag, acc0, 0, 0, 0);
            acc1 = __builtin_amdgcn_mfma_f32_16x16x32_bf16(af[1][tap], bfrag, acc1, 0, 0, 0);
        }
    }

    float* op = out + (size_t)b * C * HW + h * W + pw;
    #pragma unroll
    for (int r = 0; r < 4; ++r) {
        op[(size_t)(q * 4 + r) * HW]        = acc0[r];
        op[(size_t)(16 + q * 4 + r) * HW]   = acc1[r];
    }
}

extern "C" void kernel_launch(void* const* d_in, const int* in_sizes, int n_in,
                              void* d_out, int out_size, void* d_ws, size_t ws_size,
                              hipStream_t stream) {
    const float* x      = (const float*)d_in[0];
    const float* depth  = (const float*)d_in[1];
    const float* weight = (const float*)d_in[2];
    const float* bias   = (const float*)d_in[3];
    float* out          = (float*)d_out;

    unsigned* xp  = (unsigned*)((char*)d_ws + XOFF);
    float2*   dpk = (float2*)  ((char*)d_ws + DOFF);
    uint4*    wpk = (uint4*)   ((char*)d_ws + WOFF);

    hipLaunchKernelGGL(pack_x,      dim3(2 * 512 * 8), dim3(256), 0, stream, x, xp);
    hipLaunchKernelGGL(pack_d,      dim3(2 * HW / 256), dim3(256), 0, stream, depth, dpk);
    hipLaunchKernelGGL(pack_border, dim3(17),           dim3(256), 0, stream, xp, dpk);
    hipLaunchKernelGGL(pack_w,      dim3(5),            dim3(256), 0, stream, weight, wpk);
    hipLaunchKernelGGL(depthconv_main, dim3(2 * 512 * 8), dim3(256), 0, stream,
                       xp, dpk, wpk, bias, out);
}

// Round 6
// 160.135 us; speedup vs baseline: 2.5898x; 1.0412x over previous
//
#include <hip/hip_runtime.h>

typedef _Float16 half8 __attribute__((ext_vector_type(8)));
typedef float floatx4 __attribute__((ext_vector_type(4)));

constexpr int C  = 32, H = 512, W = 512, HW = H * W;
constexpr int Hp = 514, Wp = 514;               // padded (1-px halo)
constexpr int NPX = 2 * Hp * Wp;                // padded pixels, both batches

// ws layout (bytes): x_pack (padded NHWC fp16) | d_pack (float2 em,ep) | w_pack
constexpr size_t XOFF = 0;
constexpr size_t XSZ  = (size_t)NPX * 64;        // 32 ch * 2 B
constexpr size_t DOFF = XOFF + XSZ;
constexpr size_t DSZ  = (size_t)NPX * 8;
constexpr size_t WOFF = DOFF + DSZ;
// total required: ~38.1 MB <= ws_size (validated in Round 5)

__device__ __forceinline__ unsigned pack2h(float lo, float hi) {
    unsigned a = (unsigned)__builtin_bit_cast(unsigned short, (_Float16)lo);
    unsigned b = (unsigned)__builtin_bit_cast(unsigned short, (_Float16)hi);
    return a | (b << 16);
}

// ---- ONE pack kernel:
//  blocks [0,2048): x NCHW fp32 -> padded NHWC fp16 (4 rows x 64 px x 32 ch per block,
//                   LDS transpose) + fused depth -> (exp(-8.3d), exp(+8.3d))
//  blocks [2048,2065): zero the 1-px halo border of xp/dpk (border taps -> exact 0)
//  blocks [2065,2070): weights -> per-lane fp16 A-fragment uint4s
__global__ __launch_bounds__(256) void pack_all(
    const float* __restrict__ x, const float* __restrict__ depth,
    const float* __restrict__ weight,
    unsigned* __restrict__ xp, float2* __restrict__ dpk, uint4* __restrict__ wp)
{
    const int bid = blockIdx.x;
    const int tid = threadIdx.x;

    if (bid >= 2048) {
        if (bid < 2065) {                        // ---- border zero
            int i = (bid - 2048) * 256 + tid;
            if (i >= 4104) return;               // 2 * (2*514 + 2*512)
            int b = i / 2052, r = i % 2052;
            int hh, ww;
            if (r < 514)       { hh = 0;   ww = r; }
            else if (r < 1028) { hh = 513; ww = r - 514; }
            else { int j = r - 1028; hh = 1 + (j >> 1); ww = (j & 1) ? 513 : 0; }
            size_t ppx = ((size_t)(b * Hp + hh)) * Wp + ww;
            uint4 z = {0u, 0u, 0u, 0u};
            uint4* p = (uint4*)(xp + ppx * 16);
            p[0] = z; p[1] = z; p[2] = z; p[3] = z;
            dpk[ppx] = make_float2(0.f, 0.f);
        } else {                                 // ---- weight pack (fp16 A-frags)
            int j = (bid - 2065) * 256 + tid;
            if (j >= 1152) return;               // 9 taps * 2 halves * 64 lanes
            int lane = j & 63, half = (j >> 6) & 1, tap = j >> 7;
            int o = half * 16 + (lane & 15), q = lane >> 4;
            uint4 v;
            v.x = pack2h(weight[(o * 32 + q * 8 + 0) * 9 + tap], weight[(o * 32 + q * 8 + 1) * 9 + tap]);
            v.y = pack2h(weight[(o * 32 + q * 8 + 2) * 9 + tap], weight[(o * 32 + q * 8 + 3) * 9 + tap]);
            v.z = pack2h(weight[(o * 32 + q * 8 + 4) * 9 + tap], weight[(o * 32 + q * 8 + 5) * 9 + tap]);
            v.w = pack2h(weight[(o * 32 + q * 8 + 6) * 9 + tap], weight[(o * 32 + q * 8 + 7) * 9 + tap]);
            wp[j] = v;
        }
        return;
    }

    // ---- x transpose: 4 rows x 64 px x 32 ch per block
    __shared__ float t[4][32][65];               // pitch 65: 2-way bank alias (free)
    const int wseg = bid & 7, hseg = (bid >> 3) & 127, b = bid >> 10;
    const int h0 = hseg * 4, w0 = wseg * 64;

    const float* xb = x + (size_t)b * C * HW + h0 * W + w0;
    #pragma unroll
    for (int p = 0; p < 8; ++p) {                // 8 independent float4 loads
        int slot = p * 256 + tid;                // (r, c, f4)
        int r = slot >> 9, c = (slot >> 4) & 31, f4 = slot & 15;
        float4 v = *(const float4*)(xb + (size_t)c * HW + r * W + f4 * 4);
        t[r][c][f4 * 4 + 0] = v.x; t[r][c][f4 * 4 + 1] = v.y;
        t[r][c][f4 * 4 + 2] = v.z; t[r][c][f4 * 4 + 3] = v.w;
    }

    // fused depth pack (no LDS dependence): one px per thread (4 rows x 64 px)
    {
        int rr = tid >> 6, ww = tid & 63;
        float d = depth[(size_t)b * HW + (h0 + rr) * W + w0 + ww];
        size_t ppx = ((size_t)(b * Hp + h0 + rr + 1)) * Wp + (w0 + 1 + ww);
        dpk[ppx] = make_float2(__expf(-8.3f * d), __expf(8.3f * d));
    }
    __syncthreads();

    const int px = tid >> 2, q = tid & 3;        // 4 threads per pixel
    #pragma unroll
    for (int r = 0; r < 4; ++r) {
        uint4 o;
        o.x = pack2h(t[r][q * 8 + 0][px], t[r][q * 8 + 1][px]);
        o.y = pack2h(t[r][q * 8 + 2][px], t[r][q * 8 + 3][px]);
        o.z = pack2h(t[r][q * 8 + 4][px], t[r][q * 8 + 5][px]);
        o.w = pack2h(t[r][q * 8 + 6][px], t[r][q * 8 + 7][px]);
        size_t ppx = ((size_t)(b * Hp + h0 + r + 1)) * Wp + (w0 + 1 + px);
        *(uint4*)(xp + ppx * 16 + q * 4) = o;
    }
}

// ---- main conv: no LDS, no syncthreads. B-frag = one coalesced dwordx4 per lane;
// sim scaling via packed fp16 muls (v_pk_mul_f16).
__global__ __launch_bounds__(256) void depthconv_main(
    const unsigned* __restrict__ xp,
    const float2*   __restrict__ dpk,
    const uint4*    __restrict__ wp,
    const float*    __restrict__ bias,
    float*          __restrict__ out)
{
    const int bid  = blockIdx.x;                 // b(2) x h(512) x wseg(8)
    const int wseg = bid & 7, h = (bid >> 3) & 511, b = bid >> 12;
    const int lane = threadIdx.x & 63, wid = threadIdx.x >> 6;
    const int nn   = lane & 15, q = lane >> 4;
    const int pw   = wseg * 64 + wid * 16 + nn;  // output column 0..511

    // A fragments (18 x 16 B, L1-hot)
    half8 af[2][9];
    #pragma unroll
    for (int tap = 0; tap < 9; ++tap) {
        af[0][tap] = __builtin_bit_cast(half8, wp[(tap * 2 + 0) * 64 + lane]);
        af[1][tap] = __builtin_bit_cast(half8, wp[(tap * 2 + 1) * 64 + lane]);
    }

    floatx4 acc0, acc1;                          // C/D: col=nn, row(o)=4q+reg
    #pragma unroll
    for (int r = 0; r < 4; ++r) {
        acc0[r] = bias[q * 4 + r];
        acc1[r] = bias[16 + q * 4 + r];
    }

    const size_t rowbase = ((size_t)(b * Hp + h)) * Wp + pw;  // padded (h+ki, pw+kj)
    const float2 dc = dpk[rowbase + Wp + 1];     // center (em_c, ep_c)

    #pragma unroll
    for (int ki = 0; ki < 3; ++ki) {
        #pragma unroll
        for (int kj = 0; kj < 3; ++kj) {
            const int tap = ki * 3 + kj;
            const size_t np = rowbase + (size_t)ki * Wp + kj;
            float2 dn = dpk[np];
            float s = fminf(dn.y * dc.x, dn.x * dc.y);     // exp(-8.3|dc-dn|)
            _Float16 hs = (_Float16)s;
            half8 sv = { hs, hs, hs, hs, hs, hs, hs, hs };

            half8 xv = __builtin_bit_cast(half8, *(const uint4*)(xp + np * 16 + q * 4));
            half8 bfrag = xv * sv;               // 4x v_pk_mul_f16

            acc0 = __builtin_amdgcn_mfma_f32_16x16x32_f16(af[0][tap], bfrag, acc0, 0, 0, 0);
            acc1 = __builtin_amdgcn_mfma_f32_16x16x32_f16(af[1][tap], bfrag, acc1, 0, 0, 0);
        }
    }

    float* op = out + (size_t)b * C * HW + h * W + pw;
    #pragma unroll
    for (int r = 0; r < 4; ++r) {
        op[(size_t)(q * 4 + r) * HW]        = acc0[r];
        op[(size_t)(16 + q * 4 + r) * HW]   = acc1[r];
    }
}

extern "C" void kernel_launch(void* const* d_in, const int* in_sizes, int n_in,
                              void* d_out, int out_size, void* d_ws, size_t ws_size,
                              hipStream_t stream) {
    const float* x      = (const float*)d_in[0];
    const float* depth  = (const float*)d_in[1];
    const float* weight = (const float*)d_in[2];
    const float* bias   = (const float*)d_in[3];
    float* out          = (float*)d_out;

    unsigned* xp  = (unsigned*)((char*)d_ws + XOFF);
    float2*   dpk = (float2*)  ((char*)d_ws + DOFF);
    uint4*    wpk = (uint4*)   ((char*)d_ws + WOFF);

    hipLaunchKernelGGL(pack_all, dim3(2070), dim3(256), 0, stream,
                       x, depth, weight, xp, dpk, wpk);
    hipLaunchKernelGGL(depthconv_main, dim3(2 * 512 * 8), dim3(256), 0, stream,
                       xp, dpk, wpk, bias, out);
}